// Round 10
// baseline (135.433 us; speedup 1.0000x reference)
//
#include <hip/hip_runtime.h>
#include <math.h>

// SplitBruteForceAntisymmetrize: N=6 (720 perms), D=3, HID=64, BATCH=2048.
// Math (R3+R4, absmax 0.1875): F[j][i]=exp2(K*c[j][i]); pair {a<b} after
// prefix P: d = P*(v-u)/(P^2*u*v+P*(u+v)+1); depth-3 triple-combine -> one
// rcp + one fp64 fold per 6 perms. Packed dual-batch (R7): 2 batch elems in
// v2f halves. Named members via if-constexpr getters (R8): no alloca/scratch.
// R10 = R8 config (best: 87.07 us wall, kernel ~22.6 us) + DIAGNOSTIC PROBE:
//   R8's kernel sits below the 39.5us ws-poison fills, so rocprof top-5 has
//   shown zero kernel counters since R7. antisym_probe = same body x3 reps
//   (rotated batch indices, unroll-disabled -> no CSE, same I$ shape),
//   per-thread result to d_ws -> ~65us dispatch, visible in top-5 with
//   VGPR_Count / VALUBusy / OccupancyPercent for THIS code shape.
//   Decision rule: VGPR~90 -> tables still in scratch; VALUBusy>=75% ->
//   issue-bound (polish then ceiling); <=55% -> latency-bound (ILP surgery).
//   Wall regresses this round by design; revert to R8-only next round.

typedef float  v2f __attribute__((ext_vector_type(2)));
typedef double v2d __attribute__((ext_vector_type(2)));

__device__ __forceinline__ float fexp2(float x) {
#if __has_builtin(__builtin_amdgcn_exp2f)
    return __builtin_amdgcn_exp2f(x);
#else
    return exp2f(x);
#endif
}
__device__ __forceinline__ float frcp(float x) {
#if __has_builtin(__builtin_amdgcn_rcpf)
    return __builtin_amdgcn_rcpf(x);
#else
    return 1.0f / x;
#endif
}
__device__ __forceinline__ v2f vrcp(v2f v) {
    v2f r; r.x = frcp(v.x); r.y = frcp(v.y); return r;
}
__device__ __forceinline__ v2f vfma(v2f a, v2f b, v2f c) {
    return __builtin_elementwise_fma(a, b, c);
}

constexpr int lowest_free(unsigned used) {
    for (int j = 0; j < 6; ++j)
        if (!(used & (1u << j))) return j;
    return -1;
}

// ---- named-member tables (NO arrays -> no alloca -> no scratch) ----
#define FJI_LIST(X) X(0,0) X(0,1) X(0,2) X(0,3) X(1,0) X(1,1) X(1,2) X(1,3) \
                    X(2,0) X(2,1) X(2,2) X(2,3) X(3,0) X(3,1) X(3,2) X(3,3) \
                    X(4,0) X(4,1) X(4,2) X(4,3) X(5,0) X(5,1) X(5,2) X(5,3)
#define J6_LIST(X) X(0) X(1) X(2) X(3) X(4) X(5)
#define PAIR_LIST(X) X(0,1) X(0,2) X(0,3) X(0,4) X(0,5) X(1,2) X(1,3) X(1,4) \
                     X(1,5) X(2,3) X(2,4) X(2,5) X(3,4) X(3,5) X(4,5)
#define WC_LIST(X) X(0) X(1) X(2) X(3) X(4) X(5) X(6) X(7) X(8) X(9) X(10) \
                   X(11) X(12) X(13) X(14) X(15) X(16) X(17)

struct Tbl {
#define M(j,i) v2f F##j##_##i;
    FJI_LIST(M)
#undef M
#define M(j) v2f FA##j; v2f FB##j; v2f G##j;
    J6_LIST(M)
#undef M
#define M(a,b) v2f W##a##b; v2f S##a##b; v2f Q##a##b;
    PAIR_LIST(M)
#undef M
};

template <int J, int I> __device__ __forceinline__ v2f getF(const Tbl& T) {
#define M(j,i) if constexpr (J==j && I==i) return T.F##j##_##i;
    FJI_LIST(M)
#undef M
    __builtin_unreachable();
}
template <int J, int I> __device__ __forceinline__ void setF(Tbl& T, v2f v) {
#define M(j,i) if constexpr (J==j && I==i) T.F##j##_##i = v;
    FJI_LIST(M)
#undef M
}
template <int J> __device__ __forceinline__ v2f getFA(const Tbl& T) {
#define M(j) if constexpr (J==j) return T.FA##j;
    J6_LIST(M)
#undef M
    __builtin_unreachable();
}
template <int J> __device__ __forceinline__ void setFA(Tbl& T, v2f v) {
#define M(j) if constexpr (J==j) T.FA##j = v;
    J6_LIST(M)
#undef M
}
template <int J> __device__ __forceinline__ v2f getFB(const Tbl& T) {
#define M(j) if constexpr (J==j) return T.FB##j;
    J6_LIST(M)
#undef M
    __builtin_unreachable();
}
template <int J> __device__ __forceinline__ void setFB(Tbl& T, v2f v) {
#define M(j) if constexpr (J==j) T.FB##j = v;
    J6_LIST(M)
#undef M
}
template <int J> __device__ __forceinline__ v2f getG(const Tbl& T) {
#define M(j) if constexpr (J==j) return T.G##j;
    J6_LIST(M)
#undef M
    __builtin_unreachable();
}
template <int J> __device__ __forceinline__ void setG(Tbl& T, v2f v) {
#define M(j) if constexpr (J==j) T.G##j = v;
    J6_LIST(M)
#undef M
}
template <int A, int B> __device__ __forceinline__ v2f getW(const Tbl& T) {
#define M(a,b) if constexpr (A==a && B==b) return T.W##a##b;
    PAIR_LIST(M)
#undef M
    __builtin_unreachable();
}
template <int A, int B> __device__ __forceinline__ void setW(Tbl& T, v2f v) {
#define M(a,b) if constexpr (A==a && B==b) T.W##a##b = v;
    PAIR_LIST(M)
#undef M
}
template <int A, int B> __device__ __forceinline__ v2f getS(const Tbl& T) {
#define M(a,b) if constexpr (A==a && B==b) return T.S##a##b;
    PAIR_LIST(M)
#undef M
    __builtin_unreachable();
}
template <int A, int B> __device__ __forceinline__ void setS(Tbl& T, v2f v) {
#define M(a,b) if constexpr (A==a && B==b) T.S##a##b = v;
    PAIR_LIST(M)
#undef M
}
template <int A, int B> __device__ __forceinline__ v2f getQ(const Tbl& T) {
#define M(a,b) if constexpr (A==a && B==b) return T.Q##a##b;
    PAIR_LIST(M)
#undef M
    __builtin_unreachable();
}
template <int A, int B> __device__ __forceinline__ void setQ(Tbl& T, v2f v) {
#define M(a,b) if constexpr (A==a && B==b) T.Q##a##b = v;
    PAIR_LIST(M)
#undef M
}

// per-lane weights, pre-scaled by K = 2*log2(e)
struct Wgt {
#define M(r) float c##r;
    WC_LIST(M)
#undef M
    float b1s;
};
template <int R> __device__ __forceinline__ float getWC(const Wgt& W) {
#define M(r) if constexpr (R==r) return W.c##r;
    WC_LIST(M)
#undef M
    __builtin_unreachable();
}

// ---- setup: c -> exp2 -> F/FA/FB/G, then pair tables W/S/Q ----
template <int J, int I>
__device__ __forceinline__ void setupJI(Tbl& T, const Wgt& Wg,
                                        v2f x0, v2f x1, v2f x2) {
    v2f c = x0 * getWC<3*I+0>(Wg) + x1 * getWC<3*I+1>(Wg) + x2 * getWC<3*I+2>(Wg);
    if constexpr (I == 0) { c.x += Wg.b1s; c.y += Wg.b1s; }
    v2f e; e.x = fexp2(c.x); e.y = fexp2(c.y);
    if constexpr (I < 4) setF<J, I>(T, e);
    else if constexpr (I == 4) setFA<J>(T, e);
    else { setFB<J>(T, e); setG<J>(T, getFA<J>(T) * e); }
}

template <int J>
__device__ __forceinline__ void setupJ(Tbl& T, const Wgt& Wg,
                                       const float* xa, const float* xb) {
    v2f x0, x1, x2;
    x0.x = xa[3*J+0]; x0.y = xb[3*J+0];
    x1.x = xa[3*J+1]; x1.y = xb[3*J+1];
    x2.x = xa[3*J+2]; x2.y = xb[3*J+2];
    setupJI<J,0>(T, Wg, x0, x1, x2);
    setupJI<J,1>(T, Wg, x0, x1, x2);
    setupJI<J,2>(T, Wg, x0, x1, x2);
    setupJI<J,3>(T, Wg, x0, x1, x2);
    setupJI<J,4>(T, Wg, x0, x1, x2);
    setupJI<J,5>(T, Wg, x0, x1, x2);
}

template <int A, int B>
__device__ __forceinline__ void setupPair(Tbl& T) {
    v2f u = getFA<A>(T) * getFB<B>(T);   // (a@4, b@5)
    v2f v = getFA<B>(T) * getFB<A>(T);   // (b@4, a@5)
    setW<A,B>(T, v - u);
    setS<A,B>(T, u + v);
    setQ<A,B>(T, getG<A>(T) * getG<B>(T));
}

// ---- DFS over slots 0..2; P = running packed product ----
template <int LVL, unsigned USED, int PAR>
struct Node {
    template <int J>
    static __device__ __forceinline__ void step(const Tbl& T, v2f P,
                                                v2d& a0, v2d& a1) {
        if constexpr ((USED & (1u << J)) == 0) {
            constexpr int par2 = PAR ^ (__builtin_popcount(USED >> (J + 1)) & 1);
            if constexpr (LVL == 0)
                Node<1, (1u << J), par2>::go(T, getF<J,0>(T), a0, a1);
            else
                Node<LVL + 1, USED | (1u << J), par2>::go(T, P * getF<J,LVL>(T), a0, a1);
        }
    }
    static __device__ __forceinline__ void go(const Tbl& T, v2f P,
                                              v2d& a0, v2d& a1) {
        step<0>(T, P, a0, a1);
        step<1>(T, P, a0, a1);
        step<2>(T, P, a0, a1);
        step<3>(T, P, a0, a1);
        step<4>(T, P, a0, a1);
        step<5>(T, P, a0, a1);
    }
};

template <unsigned USED, int PAR>
struct Node<3, USED, PAR> {
    template <int X, int A, int B>
    static __device__ __forceinline__ v2f child_den(const Tbl& T, v2f P3,
                                                    v2f& n) {
        v2f P4 = P3 * getF<X,3>(T);
        v2f Q  = P4 * P4;
        n = P4 * getW<A,B>(T);
        v2f one; one.x = 1.0f; one.y = 1.0f;
        return vfma(Q, getQ<A,B>(T), vfma(P4, getS<A,B>(T), one));
    }
    template <int X, int A, int B>
    static constexpr int child_sign() {
        constexpr unsigned U4 = USED | (1u << X);
        constexpr int inv_x = __builtin_popcount(USED >> (X + 1));
        constexpr int inv_a = __builtin_popcount(U4 >> (A + 1));
        constexpr int inv_b = __builtin_popcount((U4 | (1u << A)) >> (B + 1));
        return (PAR ^ ((inv_x + inv_a + inv_b) & 1));
    }
    static __device__ __forceinline__ void go(const Tbl& T, v2f P3,
                                              v2d& a0, v2d& a1) {
        constexpr int x0 = lowest_free(USED);
        constexpr int x1 = lowest_free(USED | (1u << x0));
        constexpr int x2 = lowest_free(USED | (1u << x0) | (1u << x1));

        v2f n0, n1, n2;
        v2f den0 = child_den<x0, x1, x2>(T, P3, n0);
        v2f den1 = child_den<x1, x0, x2>(T, P3, n1);
        v2f den2 = child_den<x2, x0, x1>(T, P3, n2);

        v2f n0s = child_sign<x0, x1, x2>() ? -n0 : n0;
        v2f n1s = child_sign<x1, x0, x2>() ? -n1 : n1;
        v2f n2s = child_sign<x2, x0, x1>() ? -n2 : n2;

        v2f d01 = den0 * den1;
        v2f den = d01 * den2;
        v2f t01 = vfma(n0s, den1, n1s * den0);
        v2f num = vfma(t01, den2, n2s * d01);
        v2f r = num * vrcp(den);
        v2d rd = __builtin_convertvector(r, v2d);
        if constexpr (USED & 1) a1 += rd;
        else                    a0 += rd;
    }
};

// ---- shared per-wave body: packed psi-sum S for 2 batch elems ----
__device__ __forceinline__ void compute_pair(const Wgt& Wg, const float* xa,
                                             const float* xb,
                                             double& s0, double& s1) {
    Tbl T;
    setupJ<0>(T, Wg, xa, xb);
    setupJ<1>(T, Wg, xa, xb);
    setupJ<2>(T, Wg, xa, xb);
    setupJ<3>(T, Wg, xa, xb);
    setupJ<4>(T, Wg, xa, xb);
    setupJ<5>(T, Wg, xa, xb);
#define M(a,b) setupPair<a,b>(T);
    PAIR_LIST(M)
#undef M
    v2d acc0; acc0.x = 0.0; acc0.y = 0.0;
    v2d acc1; acc1.x = 0.0; acc1.y = 0.0;
    v2f one; one.x = 1.0f; one.y = 1.0f;
    Node<0, 0u, 0>::go(T, one, acc0, acc1);
    s0 = acc0.x + acc1.x;
    s1 = acc0.y + acc1.y;
}

// ---- real kernel (R8 config, bit-identical output) ----
__global__ __launch_bounds__(256, 2) void antisym_kernel(
    const float* __restrict__ x1, const float* __restrict__ x2,
    const float* __restrict__ W1a, const float* __restrict__ b1a,
    const float* __restrict__ W2a,
    const float* __restrict__ W1b, const float* __restrict__ b1b,
    const float* __restrict__ W2b,
    float* __restrict__ out, int B) {
    __shared__ float lds_log[8];   // [(pair*2+k)*2 + ch]

    const int lane = threadIdx.x & 63;
    const int wave = threadIdx.x >> 6;
    const int pi = wave >> 1;
    const int ch = wave & 1;

    const float* x  = ch ? x2  : x1;
    const float* W1 = ch ? W1b : W1a;
    const float* b1 = ch ? b1b : b1a;
    const float* W2 = ch ? W2b : W2a;

    const int b0 = blockIdx.x * 4 + pi * 2;
    const int b1i = b0 + 1;
    const int b1c = (b1i < B) ? b1i : (B - 1);

    if (b0 < B) {
        const float K = 2.8853900817779268f;  // 2*log2(e)
        Wgt Wg;
#define M(r) Wg.c##r = W1[r * 64 + lane] * K;
        WC_LIST(M)
#undef M
        Wg.b1s = b1[lane] * K;
        const float w2v = W2[lane];

        double s0, s1;
        compute_pair(Wg, x + b0 * 18, x + b1c * 18, s0, s1);

        double v0 = (double)w2v * s0 * -2.0;
        double v1 = (double)w2v * s1 * -2.0;
#pragma unroll
        for (int off = 32; off > 0; off >>= 1) {
            v0 += __shfl_xor(v0, off, 64);
            v1 += __shfl_xor(v1, off, 64);
        }
        if (lane == 0) {
            lds_log[(pi * 2 + 0) * 2 + ch] = logf(fabsf((float)v0));
            if (b1i < B)
                lds_log[(pi * 2 + 1) * 2 + ch] = logf(fabsf((float)v1));
        }
    }
    __syncthreads();
    if (threadIdx.x < 4) {
        int bb = blockIdx.x * 4 + threadIdx.x;
        if (bb < B)
            out[bb] = lds_log[threadIdx.x * 2 + 0] + lds_log[threadIdx.x * 2 + 1];
    }
}

// ---- diagnostic probe: same body x3 (rotated b, no CSE), writes d_ws ----
__global__ __launch_bounds__(256, 2) void antisym_probe(
    const float* __restrict__ x1, const float* __restrict__ x2,
    const float* __restrict__ W1a, const float* __restrict__ b1a,
    const float* __restrict__ W1b, const float* __restrict__ b1b,
    double* __restrict__ ws, int B) {
    const int lane = threadIdx.x & 63;
    const int wave = threadIdx.x >> 6;
    const int pi = wave >> 1;
    const int ch = wave & 1;

    const float* x  = ch ? x2  : x1;
    const float* W1 = ch ? W1b : W1a;
    const float* b1 = ch ? b1b : b1a;

    const float K = 2.8853900817779268f;
    Wgt Wg;
#define M(r) Wg.c##r = W1[r * 64 + lane] * K;
    WC_LIST(M)
#undef M
    Wg.b1s = b1[lane] * K;

    double s = 0.0;
#pragma unroll 1
    for (int rep = 0; rep < 3; ++rep) {
        int b0 = (blockIdx.x * 4 + pi * 2 + rep * 683) % B;
        int bb = (b0 + 1) % B;
        double s0, s1;
        compute_pair(Wg, x + b0 * 18, x + bb * 18, s0, s1);
        s += s0 + s1;
    }
    ws[blockIdx.x * 256 + threadIdx.x] = s;  // defeat DCE; d_ws is scratch
}

extern "C" void kernel_launch(void* const* d_in, const int* in_sizes, int n_in,
                              void* d_out, int out_size, void* d_ws, size_t ws_size,
                              hipStream_t stream) {
    const float* x1  = (const float*)d_in[0];
    const float* x2  = (const float*)d_in[1];
    const float* W1a = (const float*)d_in[2];
    const float* b1a = (const float*)d_in[3];
    const float* W2a = (const float*)d_in[4];
    // d_in[5] = b2a: contributes b2 * sum(signs) = 0 exactly
    const float* W1b = (const float*)d_in[6];
    const float* b1b = (const float*)d_in[7];
    const float* W2b = (const float*)d_in[8];
    // d_in[9] = b2b: same

    const int B = in_sizes[0] / 18;  // (B, 6, 3) flattened
    float* out = (float*)d_out;

    dim3 grid((B + 3) / 4), block(256);
    hipLaunchKernelGGL(antisym_kernel, grid, block, 0, stream,
                       x1, x2, W1a, b1a, W2a, W1b, b1b, W2b, out, B);
    // diagnostic dispatch (counters only; output unused)
    hipLaunchKernelGGL(antisym_probe, grid, block, 0, stream,
                       x1, x2, W1a, b1a, W1b, b1b, (double*)d_ws, B);
}

// Round 11
// 86.760 us; speedup vs baseline: 1.5610x; 1.5610x over previous
//
#include <hip/hip_runtime.h>
#include <math.h>

// SplitBruteForceAntisymmetrize: N=6 (720 perms), D=3, HID=64, BATCH=2048.
// Math (R3+R4, absmax 0.1875): F[j][i]=exp2(K*c[j][i]) (K=2log2e, b1 in col
// 0); 2^{preact'} = prod_i F[perm(i)][i]; tanh = 1 - 2/(E+1); sum sign = 0.
// Pair {a<b} after prefix P: d = P*(v-u)/(P^2*u*v+P*(u+v)+1); depth-3
// triple-combine -> one rcp + one fp64 fold per 6 perms (fp64: R2 lesson —
// S ~ 1e-5 vs O(1) terms, fp32 running sums are fatal). Packed dual-batch
// (R7): 2 batch elems in v2f halves -> v_pk_* ops. Named members via
// if-constexpr getters (R8): no alloca -> no scratch.
// R11 root-cause fix from R10's probe: VGPR_Count=104 with a 256 cap and no
//   spill => the scheduler REMATERIALIZED W/S/Q at every one of 120 leaf
//   nodes (sunk setupPair into uses; ~1800 extra pk ops — matches measured
//   20.5us vs 16us no-remat model). PIN each W/S/Q value with an empty
//   inline-asm register barrier: asm-defined values cannot be remat'd or
//   sunk -> tables materialize once, live set ~194 < 256 cap, still
//   2 waves/SIMD (grid 512 = exactly 2 blocks/CU, zero tail).

typedef float  v2f __attribute__((ext_vector_type(2)));
typedef double v2d __attribute__((ext_vector_type(2)));

// Optimization barrier: forces v into a VGPR at this point; the value
// becomes opaque to rematerialization/sinking. No instruction emitted.
__device__ __forceinline__ void pin(v2f& v) { asm volatile("" : "+v"(v)); }

__device__ __forceinline__ float fexp2(float x) {
#if __has_builtin(__builtin_amdgcn_exp2f)
    return __builtin_amdgcn_exp2f(x);
#else
    return exp2f(x);
#endif
}
__device__ __forceinline__ float frcp(float x) {
#if __has_builtin(__builtin_amdgcn_rcpf)
    return __builtin_amdgcn_rcpf(x);
#else
    return 1.0f / x;
#endif
}
__device__ __forceinline__ v2f vrcp(v2f v) {
    v2f r; r.x = frcp(v.x); r.y = frcp(v.y); return r;
}
__device__ __forceinline__ v2f vfma(v2f a, v2f b, v2f c) {
    return __builtin_elementwise_fma(a, b, c);
}

constexpr int lowest_free(unsigned used) {
    for (int j = 0; j < 6; ++j)
        if (!(used & (1u << j))) return j;
    return -1;
}

// ---- named-member tables (NO arrays -> no alloca -> no scratch) ----
#define FJI_LIST(X) X(0,0) X(0,1) X(0,2) X(0,3) X(1,0) X(1,1) X(1,2) X(1,3) \
                    X(2,0) X(2,1) X(2,2) X(2,3) X(3,0) X(3,1) X(3,2) X(3,3) \
                    X(4,0) X(4,1) X(4,2) X(4,3) X(5,0) X(5,1) X(5,2) X(5,3)
#define J6_LIST(X) X(0) X(1) X(2) X(3) X(4) X(5)
#define PAIR_LIST(X) X(0,1) X(0,2) X(0,3) X(0,4) X(0,5) X(1,2) X(1,3) X(1,4) \
                     X(1,5) X(2,3) X(2,4) X(2,5) X(3,4) X(3,5) X(4,5)
#define WC_LIST(X) X(0) X(1) X(2) X(3) X(4) X(5) X(6) X(7) X(8) X(9) X(10) \
                   X(11) X(12) X(13) X(14) X(15) X(16) X(17)

struct Tbl {
#define M(j,i) v2f F##j##_##i;
    FJI_LIST(M)
#undef M
#define M(j) v2f FA##j; v2f FB##j; v2f G##j;
    J6_LIST(M)
#undef M
#define M(a,b) v2f W##a##b; v2f S##a##b; v2f Q##a##b;
    PAIR_LIST(M)
#undef M
};

template <int J, int I> __device__ __forceinline__ v2f getF(const Tbl& T) {
#define M(j,i) if constexpr (J==j && I==i) return T.F##j##_##i;
    FJI_LIST(M)
#undef M
    __builtin_unreachable();
}
template <int J, int I> __device__ __forceinline__ void setF(Tbl& T, v2f v) {
#define M(j,i) if constexpr (J==j && I==i) T.F##j##_##i = v;
    FJI_LIST(M)
#undef M
}
template <int J> __device__ __forceinline__ v2f getFA(const Tbl& T) {
#define M(j) if constexpr (J==j) return T.FA##j;
    J6_LIST(M)
#undef M
    __builtin_unreachable();
}
template <int J> __device__ __forceinline__ void setFA(Tbl& T, v2f v) {
#define M(j) if constexpr (J==j) T.FA##j = v;
    J6_LIST(M)
#undef M
}
template <int J> __device__ __forceinline__ v2f getFB(const Tbl& T) {
#define M(j) if constexpr (J==j) return T.FB##j;
    J6_LIST(M)
#undef M
    __builtin_unreachable();
}
template <int J> __device__ __forceinline__ void setFB(Tbl& T, v2f v) {
#define M(j) if constexpr (J==j) T.FB##j = v;
    J6_LIST(M)
#undef M
}
template <int J> __device__ __forceinline__ v2f getG(const Tbl& T) {
#define M(j) if constexpr (J==j) return T.G##j;
    J6_LIST(M)
#undef M
    __builtin_unreachable();
}
template <int J> __device__ __forceinline__ void setG(Tbl& T, v2f v) {
#define M(j) if constexpr (J==j) T.G##j = v;
    J6_LIST(M)
#undef M
}
template <int A, int B> __device__ __forceinline__ v2f getW(const Tbl& T) {
#define M(a,b) if constexpr (A==a && B==b) return T.W##a##b;
    PAIR_LIST(M)
#undef M
    __builtin_unreachable();
}
template <int A, int B> __device__ __forceinline__ void setW(Tbl& T, v2f v) {
#define M(a,b) if constexpr (A==a && B==b) T.W##a##b = v;
    PAIR_LIST(M)
#undef M
}
template <int A, int B> __device__ __forceinline__ v2f getS(const Tbl& T) {
#define M(a,b) if constexpr (A==a && B==b) return T.S##a##b;
    PAIR_LIST(M)
#undef M
    __builtin_unreachable();
}
template <int A, int B> __device__ __forceinline__ void setS(Tbl& T, v2f v) {
#define M(a,b) if constexpr (A==a && B==b) T.S##a##b = v;
    PAIR_LIST(M)
#undef M
}
template <int A, int B> __device__ __forceinline__ v2f getQ(const Tbl& T) {
#define M(a,b) if constexpr (A==a && B==b) return T.Q##a##b;
    PAIR_LIST(M)
#undef M
    __builtin_unreachable();
}
template <int A, int B> __device__ __forceinline__ void setQ(Tbl& T, v2f v) {
#define M(a,b) if constexpr (A==a && B==b) T.Q##a##b = v;
    PAIR_LIST(M)
#undef M
}

// per-lane weights, pre-scaled by K = 2*log2(e)
struct Wgt {
#define M(r) float c##r;
    WC_LIST(M)
#undef M
    float b1s;
};
template <int R> __device__ __forceinline__ float getWC(const Wgt& W) {
#define M(r) if constexpr (R==r) return W.c##r;
    WC_LIST(M)
#undef M
    __builtin_unreachable();
}

// ---- setup: c -> exp2 -> F/FA/FB/G, then pair tables W/S/Q (pinned) ----
template <int J, int I>
__device__ __forceinline__ void setupJI(Tbl& T, const Wgt& Wg,
                                        v2f x0, v2f x1, v2f x2) {
    v2f c = x0 * getWC<3*I+0>(Wg) + x1 * getWC<3*I+1>(Wg) + x2 * getWC<3*I+2>(Wg);
    if constexpr (I == 0) { c.x += Wg.b1s; c.y += Wg.b1s; }
    v2f e; e.x = fexp2(c.x); e.y = fexp2(c.y);
    if constexpr (I < 4) setF<J, I>(T, e);
    else if constexpr (I == 4) setFA<J>(T, e);
    else { setFB<J>(T, e); setG<J>(T, getFA<J>(T) * e); }
}

template <int J>
__device__ __forceinline__ void setupJ(Tbl& T, const Wgt& Wg,
                                       const float* xa, const float* xb) {
    v2f x0, x1, x2;
    x0.x = xa[3*J+0]; x0.y = xb[3*J+0];
    x1.x = xa[3*J+1]; x1.y = xb[3*J+1];
    x2.x = xa[3*J+2]; x2.y = xb[3*J+2];
    setupJI<J,0>(T, Wg, x0, x1, x2);
    setupJI<J,1>(T, Wg, x0, x1, x2);
    setupJI<J,2>(T, Wg, x0, x1, x2);
    setupJI<J,3>(T, Wg, x0, x1, x2);
    setupJI<J,4>(T, Wg, x0, x1, x2);
    setupJI<J,5>(T, Wg, x0, x1, x2);
}

template <int A, int B>
__device__ __forceinline__ void setupPair(Tbl& T) {
    v2f u = getFA<A>(T) * getFB<B>(T);   // (a@4, b@5)
    v2f v = getFA<B>(T) * getFB<A>(T);   // (b@4, a@5)
    v2f w = v - u;
    v2f s = u + v;
    v2f q = getG<A>(T) * getG<B>(T);
    // Pin: forbid remat/sinking of the pair tables into the 120 leaf nodes
    // (R10 probe: VGPR=104 proved the scheduler was recomputing these per
    // leaf, ~1800 extra pk ops).
    pin(w); pin(s); pin(q);
    setW<A,B>(T, w);
    setS<A,B>(T, s);
    setQ<A,B>(T, q);
}

// ---- DFS over slots 0..2; P = running packed product ----
template <int LVL, unsigned USED, int PAR>
struct Node {
    template <int J>
    static __device__ __forceinline__ void step(const Tbl& T, v2f P,
                                                v2d& a0, v2d& a1) {
        if constexpr ((USED & (1u << J)) == 0) {
            constexpr int par2 = PAR ^ (__builtin_popcount(USED >> (J + 1)) & 1);
            if constexpr (LVL == 0)
                Node<1, (1u << J), par2>::go(T, getF<J,0>(T), a0, a1);
            else
                Node<LVL + 1, USED | (1u << J), par2>::go(T, P * getF<J,LVL>(T), a0, a1);
        }
    }
    static __device__ __forceinline__ void go(const Tbl& T, v2f P,
                                              v2d& a0, v2d& a1) {
        step<0>(T, P, a0, a1);
        step<1>(T, P, a0, a1);
        step<2>(T, P, a0, a1);
        step<3>(T, P, a0, a1);
        step<4>(T, P, a0, a1);
        step<5>(T, P, a0, a1);
    }
};

// Depth-3 node: slots 0-2 placed; 3 free -> 3 children (x@slot3), each leaving
// transposition pair {a<b}; merged over common denominator.
template <unsigned USED, int PAR>
struct Node<3, USED, PAR> {
    template <int X, int A, int B>
    static __device__ __forceinline__ v2f child_den(const Tbl& T, v2f P3,
                                                    v2f& n) {
        v2f P4 = P3 * getF<X,3>(T);
        v2f Q  = P4 * P4;
        n = P4 * getW<A,B>(T);
        v2f one; one.x = 1.0f; one.y = 1.0f;
        return vfma(Q, getQ<A,B>(T), vfma(P4, getS<A,B>(T), one));
    }
    template <int X, int A, int B>
    static constexpr int child_sign() {
        constexpr unsigned U4 = USED | (1u << X);
        constexpr int inv_x = __builtin_popcount(USED >> (X + 1));
        constexpr int inv_a = __builtin_popcount(U4 >> (A + 1));
        constexpr int inv_b = __builtin_popcount((U4 | (1u << A)) >> (B + 1));
        return (PAR ^ ((inv_x + inv_a + inv_b) & 1));
    }
    static __device__ __forceinline__ void go(const Tbl& T, v2f P3,
                                              v2d& a0, v2d& a1) {
        constexpr int x0 = lowest_free(USED);
        constexpr int x1 = lowest_free(USED | (1u << x0));
        constexpr int x2 = lowest_free(USED | (1u << x0) | (1u << x1));

        v2f n0, n1, n2;
        v2f den0 = child_den<x0, x1, x2>(T, P3, n0);
        v2f den1 = child_den<x1, x0, x2>(T, P3, n1);
        v2f den2 = child_den<x2, x0, x1>(T, P3, n2);

        v2f n0s = child_sign<x0, x1, x2>() ? -n0 : n0;
        v2f n1s = child_sign<x1, x0, x2>() ? -n1 : n1;
        v2f n2s = child_sign<x2, x0, x1>() ? -n2 : n2;

        v2f d01 = den0 * den1;
        v2f den = d01 * den2;
        v2f t01 = vfma(n0s, den1, n1s * den0);
        v2f num = vfma(t01, den2, n2s * d01);
        v2f r = num * vrcp(den);
        v2d rd = __builtin_convertvector(r, v2d);
        if constexpr (USED & 1) a1 += rd;
        else                    a0 += rd;
    }
};

__global__ __launch_bounds__(256, 2) void antisym_kernel(
    const float* __restrict__ x1, const float* __restrict__ x2,
    const float* __restrict__ W1a, const float* __restrict__ b1a,
    const float* __restrict__ W2a,
    const float* __restrict__ W1b, const float* __restrict__ b1b,
    const float* __restrict__ W2b,
    float* __restrict__ out, int B) {
    __shared__ float lds_log[8];   // [(pair*2+k)*2 + ch]

    const int lane = threadIdx.x & 63;
    const int wave = threadIdx.x >> 6;
    const int pi = wave >> 1;      // batch-pair index within block
    const int ch = wave & 1;

    const float* x  = ch ? x2  : x1;
    const float* W1 = ch ? W1b : W1a;
    const float* b1 = ch ? b1b : b1a;
    const float* W2 = ch ? W2b : W2a;

    const int b0 = blockIdx.x * 4 + pi * 2;
    const int b1i = b0 + 1;
    const int b1c = (b1i < B) ? b1i : (B - 1);

    if (b0 < B) {
        const float K = 2.8853900817779268f;  // 2*log2(e)
        Wgt Wg;
#define M(r) Wg.c##r = W1[r * 64 + lane] * K;
        WC_LIST(M)
#undef M
        Wg.b1s = b1[lane] * K;
        const float w2v = W2[lane];

        const float* xa = x + b0 * 18;
        const float* xb = x + b1c * 18;

        Tbl T;
        setupJ<0>(T, Wg, xa, xb);
        setupJ<1>(T, Wg, xa, xb);
        setupJ<2>(T, Wg, xa, xb);
        setupJ<3>(T, Wg, xa, xb);
        setupJ<4>(T, Wg, xa, xb);
        setupJ<5>(T, Wg, xa, xb);
#define M(a,b) setupPair<a,b>(T);
        PAIR_LIST(M)
#undef M

        v2d acc0; acc0.x = 0.0; acc0.y = 0.0;
        v2d acc1; acc1.x = 0.0; acc1.y = 0.0;
        v2f one; one.x = 1.0f; one.y = 1.0f;
        Node<0, 0u, 0>::go(T, one, acc0, acc1);

        // psi = -2 * w2 * S per job; b2 contributes b2*sum(signs) = 0
        double v0 = (double)w2v * (acc0.x + acc1.x) * -2.0;
        double v1 = (double)w2v * (acc0.y + acc1.y) * -2.0;
#pragma unroll
        for (int off = 32; off > 0; off >>= 1) {
            v0 += __shfl_xor(v0, off, 64);
            v1 += __shfl_xor(v1, off, 64);
        }
        if (lane == 0) {
            lds_log[(pi * 2 + 0) * 2 + ch] = logf(fabsf((float)v0));
            if (b1i < B)
                lds_log[(pi * 2 + 1) * 2 + ch] = logf(fabsf((float)v1));
        }
    }
    __syncthreads();
    if (threadIdx.x < 4) {
        int bb = blockIdx.x * 4 + threadIdx.x;
        if (bb < B)
            out[bb] = lds_log[threadIdx.x * 2 + 0] + lds_log[threadIdx.x * 2 + 1];
    }
}

extern "C" void kernel_launch(void* const* d_in, const int* in_sizes, int n_in,
                              void* d_out, int out_size, void* d_ws, size_t ws_size,
                              hipStream_t stream) {
    const float* x1  = (const float*)d_in[0];
    const float* x2  = (const float*)d_in[1];
    const float* W1a = (const float*)d_in[2];
    const float* b1a = (const float*)d_in[3];
    const float* W2a = (const float*)d_in[4];
    // d_in[5] = b2a: contributes b2 * sum(signs) = 0 exactly
    const float* W1b = (const float*)d_in[6];
    const float* b1b = (const float*)d_in[7];
    const float* W2b = (const float*)d_in[8];
    // d_in[9] = b2b: same

    const int B = in_sizes[0] / 18;  // (B, 6, 3) flattened
    float* out = (float*)d_out;

    dim3 grid((B + 3) / 4), block(256);  // 4 batch per block (2 per wave, packed)
    hipLaunchKernelGGL(antisym_kernel, grid, block, 0, stream,
                       x1, x2, W1a, b1a, W2a, W1b, b1b, W2b, out, B);
}